// Round 4
// baseline (67.414 us; speedup 1.0000x reference)
//
#include <hip/hip_runtime.h>

#define N 2048
#define NB 64
#define NBUCK 2048
#define PAD 192                    // max window halfwidth (fixed W=96 passed; 2x margin)
#define CUT2 0.002025f             // (0.045)^2 ; exp(-0.002025e4) = 1.6e-9
#define NEG_TAU_INV -10000.0f      // -1/tau
#define PADV 1e19f                 // sentinel: d^2*1e4 -> -inf -> exp -> 0

__device__ __forceinline__ int wave_incl_scan(int x, int lane) {
#pragma unroll
    for (int d = 1; d < 64; d <<= 1) {
        int y = __shfl_up(x, d, 64);
        if (lane >= d) x += y;
    }
    return x;
}

// Adaptive windowed softmax-weighted sum over the LDS-resident sorted row.
// Sorted rows are monotone, so the |d|>0.045 cutoff is sticky per-lane and
// near-uniform across a wave -> __all early break. Dropped terms < 1.6e-9.
// Center term is exp(0)=1 -> num=ti, den=1 start.
__device__ __forceinline__ float window_sum(const float* __restrict__ fin, int i) {
    const float ti = fin[PAD + i];
    float num = ti, den = 1.0f;
    for (int o = 1; o <= PAD; ++o) {
        const float vl = fin[PAD + i - o];
        const float vr = fin[PAD + i + o];
        const float dl = vl - ti;
        const float dr = vr - ti;
        const float dl2 = dl * dl;
        const float dr2 = dr * dr;
        const float el = __expf(dl2 * NEG_TAU_INV);
        const float er = __expf(dr2 * NEG_TAU_INV);
        num = fmaf(el, vl, num); den += el;
        num = fmaf(er, vr, num); den += er;
        if (__all((dl2 > CUT2) && (dr2 > CUT2))) break;
    }
    return num / den;
}

// ---------------- Fused: bucket sort (LDS) + windowed softmax --------------
// One block per row, 1024 threads, 2 elements/thread. Value-uniform buckets,
// LDS histogram, shfl prefix scan, atomic scatter, parallel intra-bucket
// ranking (ties broken by scatter position -> bijective ranks) into a
// sentinel-padded LDS array, then the window phase reads it in place.
// No global round-trip of the sorted row; d_ws unused.
__global__ __launch_bounds__(1024) void softsort_fused(const float* __restrict__ scores,
                                                       float* __restrict__ out) {
    __shared__ int   hist[NBUCK];       // histogram -> scatter cursor -> bucket end
    __shared__ int   pfx[NBUCK];        // bucket start (exclusive prefix)
    __shared__ float tmp[N];            // bucket-grouped, unordered within bucket
    __shared__ float fin[N + 2 * PAD];  // sentinel-padded descending-sorted row
    __shared__ float wlo[16], whi[16];
    __shared__ int   wsum[16];
    __shared__ float mm[2];

    const int b = blockIdx.x;
    const int t = threadIdx.x;
    const int w = t >> 6, lane = t & 63;
    const float* row = scores + b * N;

    const float v0 = row[t];
    const float v1 = row[t + 1024];
    hist[t] = 0; hist[t + 1024] = 0;
    if (t < 2 * PAD) fin[(t & 1) ? (N + PAD + (t >> 1)) : (t >> 1)] = PADV;

    // row min/max: wave shfl reduce -> 16 partials -> wave-0 parallel combine
    float lo = fminf(v0, v1), hi = fmaxf(v0, v1);
#pragma unroll
    for (int d = 32; d > 0; d >>= 1) {
        lo = fminf(lo, __shfl_down(lo, d, 64));
        hi = fmaxf(hi, __shfl_down(hi, d, 64));
    }
    if (lane == 0) { wlo[w] = lo; whi[w] = hi; }
    __syncthreads();
    if (w == 0) {
        float L  = (lane < 16) ? wlo[lane] : 1e30f;
        float Hh = (lane < 16) ? whi[lane] : -1e30f;
#pragma unroll
        for (int d = 8; d > 0; d >>= 1) {
            L  = fminf(L,  __shfl_down(L,  d, 64));
            Hh = fmaxf(Hh, __shfl_down(Hh, d, 64));
        }
        if (lane == 0) { mm[0] = L; mm[1] = Hh; }
    }
    __syncthreads();
    const float H = mm[1];
    const float range = H - mm[0];
    const float scale = (range > 1e-30f) ? (float)NBUCK / range : 0.0f;

    // descending bucket index: bucket 0 holds the max
    const int k0 = min(NBUCK - 1, max(0, (int)((H - v0) * scale)));
    const int k1 = min(NBUCK - 1, max(0, (int)((H - v1) * scale)));
    atomicAdd(&hist[k0], 1);
    atomicAdd(&hist[k1], 1);
    __syncthreads();

    // exclusive prefix over 2048 buckets: wave w owns chunk [w*128, w*128+128)
    const int base = w * 128;
    const int x0 = hist[base + lane];
    const int x1 = hist[base + 64 + lane];
    const int s0 = wave_incl_scan(x0, lane);
    const int tot0 = __shfl(s0, 63, 64);
    const int s1 = wave_incl_scan(x1, lane);
    const int tot1 = __shfl(s1, 63, 64);
    const int ex0 = s0 - x0;
    const int ex1 = s1 - x1 + tot0;
    if (lane == 0) wsum[w] = tot0 + tot1;
    __syncthreads();
    if (w == 0 && lane < 16) {
        const int y = wsum[lane];
        int z = y;
#pragma unroll
        for (int d = 1; d < 16; d <<= 1) {
            const int u = __shfl_up(z, d, 16);
            if (lane >= d) z += u;
        }
        wsum[lane] = z - y;     // exclusive chunk-offsets
    }
    __syncthreads();
    const int off = wsum[w];
    pfx[base + lane] = ex0 + off;
    pfx[base + 64 + lane] = ex1 + off;
    hist[base + lane] = ex0 + off;        // reuse hist as scatter cursor
    hist[base + 64 + lane] = ex1 + off;
    __syncthreads();

    // scatter into bucket-grouped order
    const int pos0 = atomicAdd(&hist[k0], 1);
    tmp[pos0] = v0;
    const int pos1 = atomicAdd(&hist[k1], 1);
    tmp[pos1] = v1;
    __syncthreads();            // after this, hist[k] == bucket end

    // parallel intra-bucket ranking into the padded sorted array
    {
        const int st = pfx[k0], en = hist[k0];
        int c = 0;
        for (int m = st; m < en; ++m) {
            const float u = tmp[m];
            c += (u > v0) || (u == v0 && m < pos0);
        }
        fin[PAD + st + c] = v0;
    }
    {
        const int st = pfx[k1], en = hist[k1];
        int c = 0;
        for (int m = st; m < en; ++m) {
            const float u = tmp[m];
            c += (u > v1) || (u == v1 && m < pos1);
        }
        fin[PAD + st + c] = v1;
    }
    __syncthreads();

    // windowed softmax straight out of LDS; outputs i = t and t + 1024
    const float o0 = window_sum(fin, t);
    const float o1 = window_sum(fin, t + 1024);
    out[b * N + t] = o0;
    out[b * N + t + 1024] = o1;
}

extern "C" void kernel_launch(void* const* d_in, const int* in_sizes, int n_in,
                              void* d_out, int out_size, void* d_ws, size_t ws_size,
                              hipStream_t stream) {
    const float* scores = (const float*)d_in[0];
    float* out = (float*)d_out;
    softsort_fused<<<NB, 1024, 0, stream>>>(scores, out);
}